// Round 5
// baseline (1205.086 us; speedup 1.0000x reference)
//
#include <hip/hip_runtime.h>
#include <hip/hip_bf16.h>

typedef __attribute__((ext_vector_type(8))) short short8;
typedef __attribute__((ext_vector_type(4))) float f32x4;

__device__ __forceinline__ unsigned short f2bf(float f) {
    __hip_bfloat16 h = __float2bfloat16(f);
    union { __hip_bfloat16 h; unsigned short u; } c; c.h = h; return c.u;
}

typedef __attribute__((address_space(1))) const unsigned int gas_u32;
typedef __attribute__((address_space(3))) unsigned int las_u32;

// async global->LDS, 16B per lane; lds dst must be the wave-uniform base
__device__ __forceinline__ void gload_lds16(const unsigned short* g, unsigned short* l) {
    __builtin_amdgcn_global_load_lds((gas_u32*)g, (las_u32*)l, 16, 0, 0);
}

#define LOG2E 1.4426950408889634f

// ---------------------------------------------------------------- fp32 -> bf16
__global__ void cvt_bf16_kernel(const float* __restrict__ src,
                                unsigned short* __restrict__ dst, long n8) {
    long stride = (long)gridDim.x * 256;
    for (long t = (long)blockIdx.x * 256 + threadIdx.x; t < n8; t += stride) {
        long i = t * 8;
        float4 f0 = *reinterpret_cast<const float4*>(src + i);
        float4 f1 = *reinterpret_cast<const float4*>(src + i + 4);
        uint4 u;
        u.x = ((unsigned)f2bf(f0.y) << 16) | f2bf(f0.x);
        u.y = ((unsigned)f2bf(f0.w) << 16) | f2bf(f0.z);
        u.z = ((unsigned)f2bf(f1.y) << 16) | f2bf(f1.x);
        u.w = ((unsigned)f2bf(f1.w) << 16) | f2bf(f1.z);
        *reinterpret_cast<uint4*>(dst + i) = u;
    }
}

// ---------------------------------------------------------------- mask pad
// mask_pad (512,112,112) in log2 domain: cols>=98 -> -1e30, pad rows -> 0
__global__ void mask_pad_kernel(const float* __restrict__ mask,
                                float* __restrict__ mask_pad) {
    int idx = blockIdx.x * 256 + threadIdx.x;
    if (idx >= 512 * 12544) return;
    int w = idx / 12544, rem = idx - w * 12544;
    int n = rem / 112, m = rem - n * 112;
    float v;
    if (m >= 98) v = -1e30f;
    else if (n >= 98) v = 0.f;
    else v = mask[w * 9604 + n * 98 + m] * LOG2E;
    mask_pad[idx] = v;
}

// ---------------------------------------------------------------- bias pad
// bias_pad (8,112,112) in log2 domain: gathered rel-pos bias, pads -> 0
__global__ void bias_pad_kernel(const float* __restrict__ bias_table,
                                const int* __restrict__ rel_index,
                                float* __restrict__ bias_pad) {
    int idx = blockIdx.x * 256 + threadIdx.x;
    if (idx >= 8 * 12544) return;
    int h = idx / 12544, rem = idx - h * 12544;
    int n = rem / 112, m = rem - n * 112;
    float v = (n < 98 && m < 98)
            ? bias_table[rel_index[n * 98 + m] * 8 + h] * LOG2E : 0.f;
    bias_pad[idx] = v;
}

// ---------------------------------------------------------------- QKV GEMM
// m97 structure: 128x128 tile, BK=64, linear bf16 LDS, global_load_lds x16B.
// Epilogue: LDS repack -> fully coalesced 16B stores; Q,K,V all (bh,n,32).
__global__ __launch_bounds__(256, 4)
void gemm_qkv_kernel(const unsigned short* __restrict__ Xb,   // (M,256) bf16
                     const unsigned short* __restrict__ Wb,   // (768,256) bf16
                     const float* __restrict__ bias,
                     unsigned short* __restrict__ qws,
                     unsigned short* __restrict__ kws,
                     unsigned short* __restrict__ vws) {
    __shared__ unsigned short sh[17408];      // 34816 B; K-loop uses first 32KB
    unsigned short* As = sh;                  // 128*64
    unsigned short* Bs = sh + 8192;           // 128*64
    const int tid = threadIdx.x;
    const int wave = tid >> 6, lane = tid & 63;
    const int q4 = lane >> 4, l16 = lane & 15;
    const int wr = wave >> 1, wc = wave & 1;

    // XCD-aware bijective swizzle (nwg = 6*1568 = 9408, 9408 % 8 == 0)
    const int nwg = gridDim.x * gridDim.y;
    const int bid = blockIdx.y * gridDim.x + blockIdx.x;
    const int swz = (bid & 7) * (nwg >> 3) + (bid >> 3);
    const int bx = swz % gridDim.x;
    const int by = swz / gridDim.x;

    const long m0 = (long)by * 128;
    const int n0 = bx * 128;

    const int srow = lane >> 3;         // row within 8-row chunk
    const int scol = (lane & 7) << 3;   // col (elems) within 64

    f32x4 acc[4][4];
#pragma unroll
    for (int i = 0; i < 4; ++i)
#pragma unroll
        for (int j = 0; j < 4; ++j) acc[i][j] = (f32x4){0.f, 0.f, 0.f, 0.f};

    for (int ks = 0; ks < 256; ks += 64) {
#pragma unroll
        for (int i = 0; i < 4; ++i) {
            int c = wave * 4 + i;                       // chunk: 8 rows x 64 cols
            gload_lds16(Xb + (m0 + c * 8 + srow) * 256 + ks + scol, &As[c * 512]);
            gload_lds16(Wb + (long)(n0 + c * 8 + srow) * 256 + ks + scol, &Bs[c * 512]);
        }
        __syncthreads();   // compiler drains vmcnt+lgkmcnt here
#pragma unroll
        for (int s = 0; s < 2; ++s) {
            short8 a[4], b[4];
#pragma unroll
            for (int i = 0; i < 4; ++i)
                a[i] = *reinterpret_cast<const short8*>(&As[(wr * 64 + i * 16 + l16) * 64 + s * 32 + q4 * 8]);
#pragma unroll
            for (int j = 0; j < 4; ++j)
                b[j] = *reinterpret_cast<const short8*>(&Bs[(wc * 64 + j * 16 + l16) * 64 + s * 32 + q4 * 8]);
#pragma unroll
            for (int i = 0; i < 4; ++i)
#pragma unroll
                for (int j = 0; j < 4; ++j)
                    acc[i][j] = __builtin_amdgcn_mfma_f32_16x16x32_bf16(a[i], b[j], acc[i][j], 0, 0, 0);
        }
        __syncthreads();
    }

    // ---------------- epilogue: acc -> LDS (bf16, stride 136) -> coalesced out
    // Q pre-scaled by (1/sqrt(32))*log2(e) for log2-domain softmax
    const float scale = (n0 < 256) ? (0.17677669529663687f * LOG2E) : 1.0f;
#pragma unroll
    for (int i = 0; i < 4; ++i) {
#pragma unroll
        for (int j = 0; j < 4; ++j) {
            int c = wc * 64 + j * 16 + l16;
            float bcol = bias[n0 + c];
#pragma unroll
            for (int r = 0; r < 4; ++r) {
                int row = wr * 64 + i * 16 + q4 * 4 + r;
                sh[row * 136 + c] = f2bf((acc[i][j][r] + bcol) * scale);
            }
        }
    }
    __syncthreads();

    const int whichb = n0 >> 8;        // 0=Q 1=K 2=V (block-uniform)
    unsigned short* dstm = (whichb == 0) ? qws : ((whichb == 1) ? kws : vws);
    const int cbase = n0 & 255;
#pragma unroll
    for (int it = 0; it < 8; ++it) {
        int id = it * 256 + tid;       // 0..2047
        int m = id >> 4;               // 0..127
        int ch = id & 15;              // 16B chunk (8 elems)
        uint4 u = *reinterpret_cast<const uint4*>(&sh[m * 136 + ch * 8]);
        long row = m0 + m;
        int b_ = (int)(row / 98);
        int n_ = (int)(row - (long)b_ * 98);
        int c = cbase + ch * 8;        // col within matrix, 0..255
        int h = c >> 5, d0 = c & 31;   // d0 in {0,8,16,24}
        *reinterpret_cast<uint4*>(dstm + (((long)(b_ * 8 + h) * 98 + n_) * 32 + d0)) = u;
    }
}

// ---------------------------------------------------------------- attention
// one block (448 thr = 7 waves) per (b,h); one 16-row S^T tile per wave.
// Q/K fragments loaded straight from global (lane-linear, row-clamped;
// K is L1-hot); only V (transposed) and P (wave-private) live in LDS.
// log2-domain softmax; normalization deferred to post-PV.
__global__ __launch_bounds__(448, 7)
void attn_kernel(const unsigned short* __restrict__ q,
                 const unsigned short* __restrict__ k,
                 const unsigned short* __restrict__ v,       // (bh,98,32)
                 const float* __restrict__ mask_pad,         // (512,112,112) *log2e
                 const float* __restrict__ bias_pad,         // (8,112,112)   *log2e
                 unsigned short* __restrict__ attn_out) {
    __shared__ unsigned short Vt[32 * 136];        // 8704 B (cols 0..127 used)
    __shared__ unsigned short Pl[7 * 16 * 136];    // 30464 B, wave-private slices

    const int tid = threadIdx.x;
    const int wave = tid >> 6, lane = tid & 63;
    const int q4 = lane >> 4, l16 = lane & 15;

    // blockIdx -> (b,h) with window locality per XCD (dispatch round-robins d&7)
    const int d0_ = blockIdx.x;
    const int xcd = d0_ & 7, jj = d0_ >> 3;
    const int w = xcd * 64 + (jj >> 5);       // 64 windows per XCD
    const int sub = jj & 31;                  // 4 b-reps x 8 heads share window w
    const int b = (sub >> 3) * 512 + w;
    const int h = sub & 7;
    const int bh = b * 8 + h;
    const long base = (long)bh * 98 * 32;

    // issue V load early; transpose-write to LDS after QK (latency hidden)
    const int vn = tid >> 2, vd0 = (tid & 3) * 8;
    uint4 vval = make_uint4(0, 0, 0, 0);
    if (vn < 98) vval = *reinterpret_cast<const uint4*>(v + base + vn * 32 + vd0);

    const int tr = wave;                   // one 16-row tile per wave
    const int n = tr * 16 + l16;           // this lane's query row (<112)
    const int nq = n < 98 ? n : 97;        // clamped: stay in this bh's slice

    // Q fragment direct from global: row nq, k-chunk q4*8 (16B, coalesced)
    short8 bq = *reinterpret_cast<const short8*>(q + base + nq * 32 + q4 * 8);

    const float* mrow = mask_pad + (long)w * 12544 + n * 112;
    const float* brow = bias_pad + (long)h * 12544 + n * 112;

    f32x4 pv[7];
#pragma unroll
    for (int i = 0; i < 7; ++i) {
        // K fragment direct from global (L1-hot after first wave); clamp row
        int kr = i * 16 + l16;
        if (i == 6) kr = kr < 98 ? kr : 97;
        short8 ak = *reinterpret_cast<const short8*>(k + base + kr * 32 + q4 * 8);
        f32x4 d = (f32x4){0.f, 0.f, 0.f, 0.f};
        d = __builtin_amdgcn_mfma_f32_16x16x32_bf16(ak, bq, d, 0, 0, 0);
        // d[r] = S[n][m]*log2e, m = i*16 + q4*4 + r (q pre-scaled)
        int m0 = i * 16 + q4 * 4;
        float4 mk = *reinterpret_cast<const float4*>(mrow + m0);
        float4 bb = *reinterpret_cast<const float4*>(brow + m0);
        pv[i][0] = d[0] + mk.x + bb.x;
        pv[i][1] = d[1] + mk.y + bb.y;
        pv[i][2] = d[2] + mk.z + bb.z;
        pv[i][3] = d[3] + mk.w + bb.w;
    }

    // V transpose into LDS (vval arrived during QK); zero cols [98,128)
    for (int idx = tid; idx < 32 * 30; idx += 448) {
        int dd = idx / 30, nn = 98 + (idx - dd * 30);
        Vt[dd * 136 + nn] = 0;
    }
    if (vn < 98) {
        union { uint4 u; unsigned short e[8]; } cv; cv.u = vval;
#pragma unroll
        for (int kk = 0; kk < 8; ++kk) Vt[(vd0 + kk) * 136 + vn] = cv.e[kk];
    }

    // softmax over m, log2 domain (in-lane 28 values + cross-quad reduce)
    float mx = -1e30f;
#pragma unroll
    for (int i = 0; i < 7; ++i)
#pragma unroll
        for (int r = 0; r < 4; ++r) mx = fmaxf(mx, pv[i][r]);
    mx = fmaxf(mx, __shfl_xor(mx, 16));
    mx = fmaxf(mx, __shfl_xor(mx, 32));
    float sm = 0.f;
#pragma unroll
    for (int i = 0; i < 7; ++i)
#pragma unroll
        for (int r = 0; r < 4; ++r) {
            float e = exp2f(pv[i][r] - mx);
            pv[i][r] = e;
            sm += e;
        }
    sm += __shfl_xor(sm, 16);
    sm += __shfl_xor(sm, 32);
    float rinv = 1.f / sm;

    // write unnormalized P (bf16) to wave-private LDS; i=7 zeroes m in [112,128)
    unsigned short* Pw = Pl + wave * 2176;
#pragma unroll
    for (int i = 0; i < 8; ++i) {
        unsigned lo = 0, hi = 0;
        if (i < 7) {
            lo = ((unsigned)f2bf(pv[i][1]) << 16) | f2bf(pv[i][0]);
            hi = ((unsigned)f2bf(pv[i][3]) << 16) | f2bf(pv[i][2]);
        }
        *reinterpret_cast<uint2*>(&Pw[l16 * 136 + i * 16 + q4 * 4]) = make_uint2(lo, hi);
    }
    __syncthreads();   // Vt ready (P is same-wave, ordered by lgkmcnt)

    // PV: A-fragment straight from P LDS, B from Vt
    f32x4 o0 = (f32x4){0.f, 0.f, 0.f, 0.f};
    f32x4 o1 = (f32x4){0.f, 0.f, 0.f, 0.f};
#pragma unroll
    for (int kc = 0; kc < 4; ++kc) {
        short8 ap  = *reinterpret_cast<const short8*>(&Pw[l16 * 136 + kc * 32 + q4 * 8]);
        short8 bv0 = *reinterpret_cast<const short8*>(&Vt[l16 * 136 + kc * 32 + q4 * 8]);
        short8 bv1 = *reinterpret_cast<const short8*>(&Vt[(16 + l16) * 136 + kc * 32 + q4 * 8]);
        o0 = __builtin_amdgcn_mfma_f32_16x16x32_bf16(ap, bv0, o0, 0, 0, 0);
        o1 = __builtin_amdgcn_mfma_f32_16x16x32_bf16(ap, bv1, o1, 0, 0, 0);
    }

    // normalize post-PV: rinv for row nn = tr*16+q4*4+r lives in lane q4*4+r
    const long obase = (long)b * 98 * 256 + h * 32;
#pragma unroll
    for (int r = 0; r < 4; ++r) {
        float rv = __shfl(rinv, q4 * 4 + r);
        int nn = tr * 16 + q4 * 4 + r;
        if (nn < 98) {
            attn_out[obase + nn * 256 + l16] = f2bf(o0[r] * rv);
            attn_out[obase + nn * 256 + 16 + l16] = f2bf(o1[r] * rv);
        }
    }
}

// ---------------------------------------------------------------- proj GEMM
__global__ __launch_bounds__(256, 4)
void gemm_proj_kernel(const unsigned short* __restrict__ Abf,  // (M,256) bf16
                      const unsigned short* __restrict__ Wb,   // (256,256) bf16
                      const float* __restrict__ bias,
                      float* __restrict__ out) {
    __shared__ unsigned short As[128 * 64];
    __shared__ unsigned short Bs[128 * 64];
    const int tid = threadIdx.x;
    const int wave = tid >> 6, lane = tid & 63;
    const int q4 = lane >> 4, l16 = lane & 15;
    const int wr = wave >> 1, wc = wave & 1;

    // XCD-aware bijective swizzle (nwg = 2*1568 = 3136, 3136 % 8 == 0)
    const int nwg = gridDim.x * gridDim.y;
    const int bid = blockIdx.y * gridDim.x + blockIdx.x;
    const int swz = (bid & 7) * (nwg >> 3) + (bid >> 3);
    const int bx = swz % gridDim.x;
    const int by = swz / gridDim.x;

    const long m0 = (long)by * 128;
    const int n0 = bx * 128;

    const int srow = lane >> 3;
    const int scol = (lane & 7) << 3;

    f32x4 acc[4][4];
#pragma unroll
    for (int i = 0; i < 4; ++i)
#pragma unroll
        for (int j = 0; j < 4; ++j) acc[i][j] = (f32x4){0.f, 0.f, 0.f, 0.f};

    for (int ks = 0; ks < 256; ks += 64) {
#pragma unroll
        for (int i = 0; i < 4; ++i) {
            int c = wave * 4 + i;
            gload_lds16(Abf + (m0 + c * 8 + srow) * 256 + ks + scol, &As[c * 512]);
            gload_lds16(Wb + (long)(n0 + c * 8 + srow) * 256 + ks + scol, &Bs[c * 512]);
        }
        __syncthreads();
#pragma unroll
        for (int s = 0; s < 2; ++s) {
            short8 a[4], b[4];
#pragma unroll
            for (int i = 0; i < 4; ++i)
                a[i] = *reinterpret_cast<const short8*>(&As[(wr * 64 + i * 16 + l16) * 64 + s * 32 + q4 * 8]);
#pragma unroll
            for (int j = 0; j < 4; ++j)
                b[j] = *reinterpret_cast<const short8*>(&Bs[(wc * 64 + j * 16 + l16) * 64 + s * 32 + q4 * 8]);
#pragma unroll
            for (int i = 0; i < 4; ++i)
#pragma unroll
                for (int j = 0; j < 4; ++j)
                    acc[i][j] = __builtin_amdgcn_mfma_f32_16x16x32_bf16(a[i], b[j], acc[i][j], 0, 0, 0);
        }
        __syncthreads();
    }
#pragma unroll
    for (int i = 0; i < 4; ++i) {
#pragma unroll
        for (int r = 0; r < 4; ++r) {
            long row = m0 + wr * 64 + i * 16 + q4 * 4 + r;
#pragma unroll
            for (int j = 0; j < 4; ++j) {
                int col = n0 + wc * 64 + j * 16 + l16;
                out[row * 256 + col] = acc[i][j][r] + bias[col];
            }
        }
    }
}

// ---------------------------------------------------------------- launch
extern "C" void kernel_launch(void* const* d_in, const int* in_sizes, int n_in,
                              void* d_out, int out_size, void* d_ws, size_t ws_size,
                              hipStream_t stream) {
    (void)in_sizes; (void)n_in; (void)out_size; (void)ws_size;
    const float* x          = (const float*)d_in[0];
    const float* mask       = (const float*)d_in[1];
    const float* qkv_w      = (const float*)d_in[2];
    const float* qkv_b      = (const float*)d_in[3];
    const float* proj_w     = (const float*)d_in[4];
    const float* proj_b     = (const float*)d_in[5];
    const float* bias_table = (const float*)d_in[6];
    const int*   rel_index  = (const int*)d_in[7];
    float* out = (float*)d_out;

    const long QN = 51380224;   // 2048*8*98*32 (bf16 elems)
    unsigned short* qws  = (unsigned short*)d_ws;
    unsigned short* kws  = qws + QN;
    unsigned short* vws  = kws + QN;
    unsigned short* aow  = vws + QN;                  // attn_out (M,256) bf16
    float* mask_padw = (float*)(aow + QN);            // 512*112*112 fp32
    float* bias_padw = mask_padw + 512 * 12544;       // 8*112*112 fp32
    unsigned short* wqkvb  = (unsigned short*)(bias_padw + 8 * 12544);  // 768*256
    unsigned short* wprojb = wqkvb + 768 * 256;                         // 256*256
    // Xb aliases aow: gemm_qkv's reads of Xb complete (stream order)
    // before attn_kernel writes attn_out into the same buffer.
    unsigned short* xb = aow;

    mask_pad_kernel<<<dim3((512 * 12544 + 255) / 256), dim3(256), 0, stream>>>(
        mask, mask_padw);
    bias_pad_kernel<<<dim3((8 * 12544 + 255) / 256), dim3(256), 0, stream>>>(
        bias_table, rel_index, bias_padw);
    cvt_bf16_kernel<<<dim3(2048), dim3(256), 0, stream>>>(x, xb, 51380224L / 8);
    cvt_bf16_kernel<<<dim3(96), dim3(256), 0, stream>>>(qkv_w, wqkvb, 196608L / 8);
    cvt_bf16_kernel<<<dim3(32), dim3(256), 0, stream>>>(proj_w, wprojb, 65536L / 8);
    gemm_qkv_kernel<<<dim3(6, 1568), dim3(256), 0, stream>>>(
        xb, wqkvb, qkv_b, qws, kws, vws);
    attn_kernel<<<dim3(16384), dim3(448), 0, stream>>>(
        qws, kws, vws, mask_padw, bias_padw, aow);
    gemm_proj_kernel<<<dim3(2, 1568), dim3(256), 0, stream>>>(
        aow, wprojb, proj_b, out);
}